// Round 6
// baseline (2767.587 us; speedup 1.0000x reference)
//
#include <hip/hip_runtime.h>

// DeepSeekV2 MoE gate — fp32 VALU GEMM, BIT-IDENTICAL arithmetic to the
// passing round-1/round-5 kernels (per (t,e): 80 K-tiles of 64 sequential
// fmafs, tile partials accumulated in order). Round-6 restructure:
//   - wave = 40-expert band, lane = token  ->  B (W) loads are WAVE-UNIFORM
//     (compiler scalarizes: SMEM/K$ path, zero LDS traffic for B)
//   - A staged in LDS [kk][tok] (lane-distinct b32 reads, free 2-way banks)
//   - per-thread tile 1 token x 40 experts, B double-buffered 1 q-group ahead
// Epilogue (softmax + grouped top-3/top-6) is round-1's code verbatim.
// Outputs (float32): [0..T*6) = topk_idx as float, [T*6..2*T*6) = weight.

#define NT    16384
#define HID   5120
#define NEXP  160
#define NKT   80               // K tiles of 64
#define S_S   164              // epilogue score row stride

__global__ __launch_bounds__(256, 1)
void moe_gate_kernel(const float* __restrict__ X,
                     const float* __restrict__ W,
                     float* __restrict__ out)
{
    // A staging ([kk][tok], 16 KB) and epilogue scores (42 KB) share LDS.
    __shared__ union alignas(16) SM {
        float As[64 * 64];     // [kk 0..63][tok 0..63]
        float S[64 * S_S];
    } u;

    const int tid = threadIdx.x;
    const int tok = tid & 63;                                  // lane = token
    const int w   = __builtin_amdgcn_readfirstlane(tid >> 6);  // wave id 0..3
    const int eb  = 40 * w;                                    // expert band
    const int tb  = blockIdx.x * 64;
    const int sr  = tid >> 2;      // staging row (token) 0..63
    const int scq = tid & 3;       // staging 16-float segment

    float acc[40];
    #pragma unroll
    for (int j = 0; j < 40; ++j) acc[j] = 0.f;

    float4 xst[4];                 // prefetched X row segment (16 floats)
    const float* xrow = X + (size_t)(tb + sr) * HID + 16 * scq;
    auto LOADX = [&](int kt) {
        #pragma unroll
        for (int i = 0; i < 4; ++i)
            xst[i] = *(const float4*)(xrow + kt * 64 + 4 * i);
    };

    const float* wb = W + (size_t)eb * HID;    // wave-uniform base

    float4 B0[10], B1[10];
    auto LOADB = [&](float4* dst, const float* wk, int c, int q) {
        #pragma unroll
        for (int j = 0; j < 10; ++j)
            dst[j] = *(const float4*)(wk + (size_t)(10 * q + j) * HID + 4 * c);
    };

    LOADX(0);

    for (int kt = 0; kt < NKT; ++kt) {
        __syncthreads();                       // prev tile's As reads done
        // transpose-store X tile: As[kk][tok], kk = 16*scq + i
        #pragma unroll
        for (int i = 0; i < 4; ++i)
            #pragma unroll
            for (int p = 0; p < 4; ++p)
                u.As[(16 * scq + 4 * i + p) * 64 + sr] = ((const float*)&xst[i])[p];
        __syncthreads();                       // As[kt] ready
        if (kt + 1 < NKT) LOADX(kt + 1);       // global prefetch (HBM, hidden)

        const float* wk = wb + kt * 64;
        float tacc[40];
        #pragma unroll
        for (int j = 0; j < 40; ++j) tacc[j] = 0.f;

        LOADB(B0, wk, 0, 0);
        for (int c = 0; c < 16; ++c) {         // kk quad = 4c..4c+3
            const float a0 = u.As[(4 * c + 0) * 64 + tok];
            const float a1 = u.As[(4 * c + 1) * 64 + tok];
            const float a2 = u.As[(4 * c + 2) * 64 + tok];
            const float a3 = u.As[(4 * c + 3) * 64 + tok];

            LOADB(B1, wk, c, 1);               // prefetch q=1
            #pragma unroll
            for (int j = 0; j < 10; ++j) {     // q=0, kk ascending per expert
                tacc[j] = fmaf(a0, B0[j].x, tacc[j]);
                tacc[j] = fmaf(a1, B0[j].y, tacc[j]);
                tacc[j] = fmaf(a2, B0[j].z, tacc[j]);
                tacc[j] = fmaf(a3, B0[j].w, tacc[j]);
            }
            LOADB(B0, wk, c, 2);               // prefetch q=2
            #pragma unroll
            for (int j = 0; j < 10; ++j) {     // q=1
                tacc[10 + j] = fmaf(a0, B1[j].x, tacc[10 + j]);
                tacc[10 + j] = fmaf(a1, B1[j].y, tacc[10 + j]);
                tacc[10 + j] = fmaf(a2, B1[j].z, tacc[10 + j]);
                tacc[10 + j] = fmaf(a3, B1[j].w, tacc[10 + j]);
            }
            LOADB(B1, wk, c, 3);               // prefetch q=3
            #pragma unroll
            for (int j = 0; j < 10; ++j) {     // q=2
                tacc[20 + j] = fmaf(a0, B0[j].x, tacc[20 + j]);
                tacc[20 + j] = fmaf(a1, B0[j].y, tacc[20 + j]);
                tacc[20 + j] = fmaf(a2, B0[j].z, tacc[20 + j]);
                tacc[20 + j] = fmaf(a3, B0[j].w, tacc[20 + j]);
            }
            LOADB(B0, wk, (c + 1) & 15, 0);    // prefetch next c's q=0
            #pragma unroll
            for (int j = 0; j < 10; ++j) {     // q=3
                tacc[30 + j] = fmaf(a0, B1[j].x, tacc[30 + j]);
                tacc[30 + j] = fmaf(a1, B1[j].y, tacc[30 + j]);
                tacc[30 + j] = fmaf(a2, B1[j].z, tacc[30 + j]);
                tacc[30 + j] = fmaf(a3, B1[j].w, tacc[30 + j]);
            }
        }
        #pragma unroll
        for (int j = 0; j < 40; ++j) acc[j] += tacc[j];
    }

    // ---- write logits to the score buffer (token = lane, 40-expert band) ----
    __syncthreads();                           // all waves done reading As
    #pragma unroll
    for (int j = 0; j < 40; ++j) u.S[tok * S_S + eb + j] = acc[j];
    __syncthreads();

    // ---- epilogue (round-1 verified): each wave owns 16 tokens ----
    const int lane = tid & 63;
    const int wv_  = tid >> 6;

    for (int it = 0; it < 16; ++it) {
        const int t = wv_ * 16 + it;

        float s0 = u.S[t * S_S + lane];
        float s1 = u.S[t * S_S + lane + 64];
        float s2 = (lane < 32) ? u.S[t * S_S + lane + 128] : -3.0e38f;

        float m = fmaxf(fmaxf(s0, s1), s2);
        #pragma unroll
        for (int d = 32; d >= 1; d >>= 1) m = fmaxf(m, __shfl_xor(m, d));

        float p0 = __expf(s0 - m);
        float p1 = __expf(s1 - m);
        float p2 = (lane < 32) ? __expf(s2 - m) : 0.f;
        float sum = p0 + p1 + p2;
        #pragma unroll
        for (int d = 32; d >= 1; d >>= 1) sum += __shfl_xor(sum, d);
        const float inv = 1.0f / sum;
        const float sc0 = p0 * inv, sc1 = p1 * inv, sc2 = p2 * inv;

        u.S[t * S_S + lane]      = sc0;
        u.S[t * S_S + lane + 64] = sc1;
        if (lane < 32) u.S[t * S_S + lane + 128] = sc2;
        __syncthreads();   // uniform across block (all waves loop 16x)

        float gm = -1.0f;
        if (lane < 8) {
            #pragma unroll
            for (int q = 0; q < 20; ++q) gm = fmaxf(gm, u.S[t * S_S + lane * 20 + q]);
        }
        unsigned gmask = 0u;
        {
            float gv[8];
            #pragma unroll
            for (int g = 0; g < 8; ++g) gv[g] = __shfl(gm, g);
            #pragma unroll
            for (int r = 0; r < 3; ++r) {
                int bi = 0; float bv2 = -2.0f;
                #pragma unroll
                for (int g = 0; g < 8; ++g) {
                    const bool taken = (gmask >> g) & 1u;
                    if (!taken && gv[g] > bv2) { bv2 = gv[g]; bi = g; }
                }
                gmask |= (1u << bi);
            }
        }

        float v0 = ((gmask >> (lane / 20)) & 1u) ? sc0 : 0.f;
        float v1 = ((gmask >> ((lane + 64) / 20)) & 1u) ? sc1 : 0.f;
        float v2 = (lane < 32) ? ((((gmask >> ((lane + 128) / 20)) & 1u) ? sc2 : 0.f))
                               : -1.f;

        float oIdx = 0.f, oW = 0.f;
        #pragma unroll
        for (int r = 0; r < 6; ++r) {
            float bv = v0; int bi = lane;
            if (v1 > bv) { bv = v1; bi = lane + 64; }
            if (v2 > bv) { bv = v2; bi = lane + 128; }
            #pragma unroll
            for (int d = 1; d < 64; d <<= 1) {
                const float ov = __shfl_xor(bv, d);
                const int   oi = __shfl_xor(bi, d);
                if (ov > bv || (ov == bv && oi < bi)) { bv = ov; bi = oi; }
            }
            if (lane == r) { oIdx = (float)bi; oW = bv * 16.0f; }
            if (bi == lane)            v0 = -1.f;
            else if (bi == lane + 64)  v1 = -1.f;
            else if (bi == lane + 128) v2 = -1.f;
        }

        const int tg = tb + t;
        if (lane < 6) {
            out[(size_t)tg * 6 + lane]                  = oIdx;
            out[(size_t)NT * 6 + (size_t)tg * 6 + lane] = oW;
        }
        __syncthreads();
    }
}

extern "C" void kernel_launch(void* const* d_in, const int* in_sizes, int n_in,
                              void* d_out, int out_size, void* d_ws, size_t ws_size,
                              hipStream_t stream)
{
    const float* X = (const float*)d_in[0];   // [4,4096,5120] fp32
    const float* W = (const float*)d_in[1];   // [160,5120] fp32
    float* out = (float*)d_out;               // [T*6 idx][T*6 weight] fp32

    moe_gate_kernel<<<NT / 64, 256, 0, stream>>>(X, W, out);
}

// Round 7
// 768.147 us; speedup vs baseline: 3.6029x; 3.6029x over previous
//
#include <hip/hip_runtime.h>

// DeepSeekV2 MoE gate — fp32 VALU GEMM, BIT-IDENTICAL arithmetic to the
// passing round-1/round-5 kernels (per (t,e): 80 K-tiles of 64 sequential
// fmafs in ascending kk, tile partials accumulated in kt order).
// Round-7 restructure of data movement only:
//   - LDS tiles k-major: As[64 tok][68], Bs[160 e][68]  (stride 68 dwords)
//     -> staging is 16 aligned ds_write_b128 (no transpose scatter)
//     -> B reads: 5 ds_read_b128 per 4-k quad, expert map e=tx+32q gives
//        bank starts 4tx mod 32 = perfectly uniform (4-cyc optimal service)
//     -> A reads: 8 b128 2-way-broadcast (free)
//   - one-quad-ahead register ping-pong (named bufs, static indices only)
// Epilogue (softmax + grouped top-3/top-6) is round-1's code verbatim.
// Outputs (float32): [0..T*6) = topk_idx as float, [T*6..2*T*6) = weight.

#define NT    16384
#define HID   5120
#define NEXP  160
#define NKT   80               // K tiles of 64
#define AS_S  68               // As row stride (dwords), = 4 mod 8
#define BS_S  68               // Bs row stride (dwords)
#define S_S   164              // epilogue score row stride

__global__ __launch_bounds__(256, 1)
void moe_gate_kernel(const float* __restrict__ X,
                     const float* __restrict__ W,
                     float* __restrict__ out)
{
    // GEMM staging (60928 B) and epilogue scores (41984 B) share LDS.
    __shared__ union alignas(16) SM {
        struct { float As[64 * AS_S]; float Bs[NEXP * BS_S]; } g;
        float S[64 * S_S];
    } u;

    const int tid = threadIdx.x;
    const int tx  = tid & 31;      // expert lane: experts tx + 32q, q=0..4
    const int oct = tid >> 5;      // token octet: tokens 8*oct..8*oct+7
    const int tb  = blockIdx.x * 64;
    const int sr  = tid >> 2;      // staging row 0..63
    const int scq = tid & 3;       // staging 16-float segment

    float acc[8][5];
    #pragma unroll
    for (int i = 0; i < 8; ++i)
        #pragma unroll
        for (int q = 0; q < 5; ++q) acc[i][q] = 0.f;

    float4 xst[4];                 // X staging: row tb+sr, 16 floats
    float4 wst[12];                // W staging: rows sr, sr+64, sr+128

    const float* xrow = X + (size_t)(tb + sr) * HID + 16 * scq;
    const float* wrow = W + (size_t)sr * HID + 16 * scq;

    auto LOADX = [&](int kt) {
        #pragma unroll
        for (int i = 0; i < 4; ++i)
            xst[i] = *(const float4*)(xrow + kt * 64 + 4 * i);
    };
    auto LOADW = [&](int kt) {
        #pragma unroll
        for (int i = 0; i < 4; ++i)
            wst[i] = *(const float4*)(wrow + kt * 64 + 4 * i);
        #pragma unroll
        for (int i = 0; i < 4; ++i)
            wst[4 + i] = *(const float4*)(wrow + (size_t)64 * HID + kt * 64 + 4 * i);
        if (sr < 32) {
            #pragma unroll
            for (int i = 0; i < 4; ++i)
                wst[8 + i] = *(const float4*)(wrow + (size_t)128 * HID + kt * 64 + 4 * i);
        }
    };
    auto STORE = [&]() {
        #pragma unroll
        for (int i = 0; i < 4; ++i)
            *(float4*)&u.g.As[sr * AS_S + 16 * scq + 4 * i] = xst[i];
        #pragma unroll
        for (int i = 0; i < 4; ++i)
            *(float4*)&u.g.Bs[sr * BS_S + 16 * scq + 4 * i] = wst[i];
        #pragma unroll
        for (int i = 0; i < 4; ++i)
            *(float4*)&u.g.Bs[(sr + 64) * BS_S + 16 * scq + 4 * i] = wst[4 + i];
        if (sr < 32) {
            #pragma unroll
            for (int i = 0; i < 4; ++i)
                *(float4*)&u.g.Bs[(sr + 128) * BS_S + 16 * scq + 4 * i] = wst[8 + i];
        }
    };

    const float* Abase = &u.g.As[(8 * oct) * AS_S];
    const float* Bbase = &u.g.Bs[tx * BS_S];

#define READQ(Aq, Bq, c) do {                                                  \
        _Pragma("unroll")                                                      \
        for (int i = 0; i < 8; ++i)                                            \
            Aq[i] = *(const float4*)(Abase + i * AS_S + 4 * (c));              \
        _Pragma("unroll")                                                      \
        for (int q = 0; q < 5; ++q)                                            \
            Bq[q] = *(const float4*)(Bbase + (32 * q) * BS_S + 4 * (c));       \
    } while (0)

#define FMAQ(Aq, Bq) do {                                                      \
        _Pragma("unroll")                                                      \
        for (int i = 0; i < 8; ++i)                                            \
            _Pragma("unroll")                                                  \
            for (int q = 0; q < 5; ++q) {                                      \
                tacc[i][q] = fmaf(Aq[i].x, Bq[q].x, tacc[i][q]);               \
                tacc[i][q] = fmaf(Aq[i].y, Bq[q].y, tacc[i][q]);               \
                tacc[i][q] = fmaf(Aq[i].z, Bq[q].z, tacc[i][q]);               \
                tacc[i][q] = fmaf(Aq[i].w, Bq[q].w, tacc[i][q]);               \
            }                                                                  \
    } while (0)

    LOADX(0); LOADW(0);

    for (int kt = 0; kt < NKT; ++kt) {
        __syncthreads();               // prev tile's LDS reads done
        STORE();
        __syncthreads();               // tile ready
        if (kt + 1 < NKT) { LOADX(kt + 1); LOADW(kt + 1); }   // global prefetch

        float tacc[8][5];
        #pragma unroll
        for (int i = 0; i < 8; ++i)
            #pragma unroll
            for (int q = 0; q < 5; ++q) tacc[i][q] = 0.f;

        float4 Aq0[8], Bq0[5], Aq1[8], Bq1[5];
        READQ(Aq0, Bq0, 0);
        #pragma unroll
        for (int c = 0; c < 16; c += 2) {
            READQ(Aq1, Bq1, c + 1);    // prefetch odd quad
            FMAQ(Aq0, Bq0);            // compute even quad (kk = 4c..4c+3)
            if (c + 2 < 16) READQ(Aq0, Bq0, c + 2);
            FMAQ(Aq1, Bq1);            // compute odd quad
        }
        #pragma unroll
        for (int i = 0; i < 8; ++i)
            #pragma unroll
            for (int q = 0; q < 5; ++q) acc[i][q] += tacc[i][q];
    }

    // ---- write logits to the score buffer (token 8*oct+i, expert tx+32q) ----
    __syncthreads();
    #pragma unroll
    for (int i = 0; i < 8; ++i) {
        const int t = 8 * oct + i;
        #pragma unroll
        for (int q = 0; q < 5; ++q) u.S[t * S_S + tx + 32 * q] = acc[i][q];
    }
    __syncthreads();

    // ---- epilogue (round-1 verified): each wave owns 16 tokens ----
    const int lane = tid & 63;
    const int wv_  = tid >> 6;

    for (int it = 0; it < 16; ++it) {
        const int t = wv_ * 16 + it;

        float s0 = u.S[t * S_S + lane];
        float s1 = u.S[t * S_S + lane + 64];
        float s2 = (lane < 32) ? u.S[t * S_S + lane + 128] : -3.0e38f;

        float m = fmaxf(fmaxf(s0, s1), s2);
        #pragma unroll
        for (int d = 32; d >= 1; d >>= 1) m = fmaxf(m, __shfl_xor(m, d));

        float p0 = __expf(s0 - m);
        float p1 = __expf(s1 - m);
        float p2 = (lane < 32) ? __expf(s2 - m) : 0.f;
        float sum = p0 + p1 + p2;
        #pragma unroll
        for (int d = 32; d >= 1; d >>= 1) sum += __shfl_xor(sum, d);
        const float inv = 1.0f / sum;
        const float sc0 = p0 * inv, sc1 = p1 * inv, sc2 = p2 * inv;

        u.S[t * S_S + lane]      = sc0;
        u.S[t * S_S + lane + 64] = sc1;
        if (lane < 32) u.S[t * S_S + lane + 128] = sc2;
        __syncthreads();   // uniform across block (all waves loop 16x)

        float gm = -1.0f;
        if (lane < 8) {
            #pragma unroll
            for (int q = 0; q < 20; ++q) gm = fmaxf(gm, u.S[t * S_S + lane * 20 + q]);
        }
        unsigned gmask = 0u;
        {
            float gv[8];
            #pragma unroll
            for (int g = 0; g < 8; ++g) gv[g] = __shfl(gm, g);
            #pragma unroll
            for (int r = 0; r < 3; ++r) {
                int bi = 0; float bv2 = -2.0f;
                #pragma unroll
                for (int g = 0; g < 8; ++g) {
                    const bool taken = (gmask >> g) & 1u;
                    if (!taken && gv[g] > bv2) { bv2 = gv[g]; bi = g; }
                }
                gmask |= (1u << bi);
            }
        }

        float v0 = ((gmask >> (lane / 20)) & 1u) ? sc0 : 0.f;
        float v1 = ((gmask >> ((lane + 64) / 20)) & 1u) ? sc1 : 0.f;
        float v2 = (lane < 32) ? ((((gmask >> ((lane + 128) / 20)) & 1u) ? sc2 : 0.f))
                               : -1.f;

        float oIdx = 0.f, oW = 0.f;
        #pragma unroll
        for (int r = 0; r < 6; ++r) {
            float bv = v0; int bi = lane;
            if (v1 > bv) { bv = v1; bi = lane + 64; }
            if (v2 > bv) { bv = v2; bi = lane + 128; }
            #pragma unroll
            for (int d = 1; d < 64; d <<= 1) {
                const float ov = __shfl_xor(bv, d);
                const int   oi = __shfl_xor(bi, d);
                if (ov > bv || (ov == bv && oi < bi)) { bv = ov; bi = oi; }
            }
            if (lane == r) { oIdx = (float)bi; oW = bv * 16.0f; }
            if (bi == lane)            v0 = -1.f;
            else if (bi == lane + 64)  v1 = -1.f;
            else if (bi == lane + 128) v2 = -1.f;
        }

        const int tg = tb + t;
        if (lane < 6) {
            out[(size_t)tg * 6 + lane]                  = oIdx;
            out[(size_t)NT * 6 + (size_t)tg * 6 + lane] = oW;
        }
        __syncthreads();
    }
#undef READQ
#undef FMAQ
}

extern "C" void kernel_launch(void* const* d_in, const int* in_sizes, int n_in,
                              void* d_out, int out_size, void* d_ws, size_t ws_size,
                              hipStream_t stream)
{
    const float* X = (const float*)d_in[0];   // [4,4096,5120] fp32
    const float* W = (const float*)d_in[1];   // [160,5120] fp32
    float* out = (float*)d_out;               // [T*6 idx][T*6 weight] fp32

    moe_gate_kernel<<<NT / 64, 256, 0, stream>>>(X, W, out);
}